// Round 13
// baseline (1190.037 us; speedup 1.0000x reference)
//
#include <hip/hip_runtime.h>

#define HH 384
#define WW 1280

typedef unsigned short u16;
typedef unsigned int u32;
typedef __attribute__((ext_vector_type(8))) short short8;
typedef __attribute__((ext_vector_type(8))) unsigned short u16x8;
typedef __attribute__((ext_vector_type(4))) float f32x4;

__device__ __forceinline__ float bf2f(u16 u){ union{u32 i;float f;}v; v.i=((u32)u)<<16; return v.f; }
__device__ __forceinline__ u16 f2bf(float f){ union{float f;u32 i;}v; v.f=f; u32 r=v.i+0x7fffu+((v.i>>16)&1u); return (u16)(r>>16); }
__device__ __forceinline__ float ftanh(float x){
  float e = __expf(2.0f*x);
  return 1.0f - 2.0f/(e+1.0f);
}
__device__ __forceinline__ void gload_lds16(const void* g, void* l){
  __builtin_amdgcn_global_load_lds((const __attribute__((address_space(1))) void*)g,
                                   (__attribute__((address_space(3))) void*)l, 16, 0, 0);
}

// Repack W1..W3 (OIHW f32) -> wf[layer][tap][oc][ic'] bf16, with the LDS read
// swizzle (byte ^= (oc&7)<<4) pre-inverted so linear global_load_lds staging
// lands the swizzled image: ic' = ic ^ ((oc&7)<<3).
__global__ __launch_bounds__(256) void prep_weights(const float* __restrict__ W1,
    const float* __restrict__ W2, const float* __restrict__ W3, u16* __restrict__ wf){
  int idx = blockIdx.x*256 + threadIdx.x;          // 3*9*64*64 = 110592
  if (idx >= 110592) return;
  int m    = idx & 63;
  int oc   = (idx>>6) & 63;
  int tap  = (idx>>12) % 9;
  int layer= idx / 36864;
  int ic   = m ^ ((oc&7)<<3);
  const float* Ws = layer==0 ? W1 : (layer==1 ? W2 : W3);
  wf[idx] = f2bf(Ws[(oc*64+ic)*9 + tap]);
}

// Layer 0: 3ch f32 NCHW -> 64ch bf16 NHWC, tanh. One pixel x 64 oc per thread.
__global__ __launch_bounds__(256) void conv0_kernel(const float* __restrict__ img,
    const float* __restrict__ W0, const float* __restrict__ b0, u16* __restrict__ out){
  int x = blockIdx.x*256 + threadIdx.x;
  int y = blockIdx.y;
  int n = blockIdx.z;
  const float* in = img + (size_t)n*3*HH*WW;
  float acc[64];
  #pragma unroll
  for (int o=0;o<64;++o) acc[o] = b0[o];
  #pragma unroll
  for (int ic=0; ic<3; ++ic)
  #pragma unroll
  for (int dy=0; dy<3; ++dy){
    int gy = y + dy - 1;
    #pragma unroll
    for (int dx=0; dx<3; ++dx){
      int gx = x + dx - 1;
      float v = 0.f;
      if (gy>=0 && gy<HH && (unsigned)gx < (unsigned)WW)
        v = in[((size_t)ic*HH + gy)*WW + gx];
      #pragma unroll
      for (int o=0;o<64;++o)
        acc[o] = fmaf(v, W0[(o*3+ic)*9 + dy*3 + dx], acc[o]);
    }
  }
  u16* op = out + ((size_t)((n*HH + y)*WW) + x)*64;
  #pragma unroll
  for (int cc=0; cc<8; ++cc){
    u16x8 v;
    #pragma unroll
    for (int k=0;k<8;++k) v[k] = f2bf(ftanh(acc[cc*8+k]));
    *(u16x8*)(op + cc*8) = v;
  }
}

// Layers 1-3: 64->64 conv, split-K MFMA. Block = 64x * 2y tile, 4 waves:
// wave (yr = wv&1, kh = wv>>1) computes 64px x 64oc over ic-half kh (K=32).
// LDS: tilebuf 34816 B -- conv phase: u16 [4 rows][66 cols][64 ic] (33792 B,
// swizzled, staged via global_load_lds from pre-swizzled src); reduce phase:
// f32 [2 yr][64 oc][68 px] (34816 B, stride 68 => every f32x4 16B-aligned).
// wbuf[2] x 8 KB double-buffer, prefetch tap+1, vmcnt(0)+s_barrier per tap.
// Total LDS 51200 B -> 3 blocks/CU (12 waves) vs previous 2 (latency-hiding).
template<bool TANH>
__global__ __launch_bounds__(256, 3) void conv64_kernel(const u16* __restrict__ in,
    const u16* __restrict__ wfL, const float* __restrict__ bias,
    const u16* __restrict__ zpad, u16* __restrict__ out){
  __shared__ __align__(16) char tilebuf[34816];
  __shared__ __align__(16) u16 wbuf[2][4096];      // 2 x 8192 B
  u16* tile = (u16*)tilebuf;
  const int tid = threadIdx.x;
  const int x0 = blockIdx.x*64;
  const int y0 = blockIdx.y*2;
  const int n  = blockIdx.z;
  const u16* inN = in + (size_t)n*HH*WW*64;

  // stage input tile: 2112 16B-chunks, chunk q = (row*66+col)*8 + j
  for (int q0 = 0; q0 < 2112; q0 += 256){
    int q = q0 + tid;
    if (q < 2112){
      int row = q / 528;
      int rem = q - row*528;
      int col = rem >> 3;
      int j   = rem & 7;
      int gy = y0 - 1 + row;
      int gx = x0 - 1 + col;
      const u16* g;
      if ((unsigned)gy < (unsigned)HH && (unsigned)gx < (unsigned)WW)
        g = inN + (((size_t)(gy*WW + gx))<<6) + ((j ^ (col&7))<<3);
      else
        g = zpad + (j<<3);
      gload_lds16(g, &tile[(size_t)(q & ~63)*8]);
    }
  }
  // stage weights taps 0,1 -> wbuf[0], wbuf[1]
  #pragma unroll
  for (int t=0; t<2; ++t)
    #pragma unroll
    for (int c=0; c<2; ++c){
      int q = c*256 + tid;
      gload_lds16(wfL + (size_t)t*4096 + (size_t)q*8, &wbuf[t][(q & ~63)*8]);
    }
  asm volatile("s_waitcnt vmcnt(2)" ::: "memory");   // drain tile+tap0; tap1 in flight
  __builtin_amdgcn_s_barrier();
  __builtin_amdgcn_sched_barrier(0);

  const int lane = tid & 63;
  const int wv  = tid >> 6;
  const int yr  = wv & 1;        // y-row within tile
  const int kh  = wv >> 1;       // ic-half
  const int l15 = lane & 15;
  const int lh  = lane >> 4;
  const int kbyte = kh*64 + lh*16;
  const int xorB  = (l15&7)<<4;

  f32x4 acc[4][4];               // [mt(px)][nt(oc)]
  #pragma unroll
  for (int mt=0;mt<4;++mt)
    #pragma unroll
    for (int nt=0;nt<4;++nt) acc[mt][nt] = (f32x4){0.f,0.f,0.f,0.f};

  #pragma unroll
  for (int tap = 0; tap < 9; ++tap){
    const int dy = tap/3, dx = tap%3;
    if (tap >= 1 && tap < 8){    // prefetch next tap's weights (tap1 staged in prologue)
      const u16* wsrc = wfL + (size_t)(tap+1)*4096;
      u16* wdst = wbuf[(tap+1)&1];
      #pragma unroll
      for (int c=0;c<2;++c){
        int q = c*256 + tid;
        gload_lds16(wsrc + (size_t)q*8, &wdst[(q & ~63)*8]);
      }
    }
    const char* wb = (const char*)wbuf[tap&1];
    const char* tb = (const char*)tile;
    const int xorA = ((l15 + dx)&7)<<4;
    short8 a[4], w[4];
    #pragma unroll
    for (int mt=0; mt<4; ++mt){
      int col = mt*16 + l15 + dx;
      a[mt] = *(const short8*)(tb + ((yr+dy)*66 + col)*128 + (kbyte ^ xorA));
    }
    #pragma unroll
    for (int nt=0; nt<4; ++nt)
      w[nt] = *(const short8*)(wb + (nt*16+l15)*128 + (kbyte ^ xorB));
    #pragma unroll
    for (int mt=0; mt<4; ++mt)
      #pragma unroll
      for (int nt=0; nt<4; ++nt)
        acc[mt][nt] = __builtin_amdgcn_mfma_f32_16x16x32_bf16(a[mt], w[nt], acc[mt][nt], 0,0,0);
    if (tap < 8){
      asm volatile("s_waitcnt vmcnt(0)" ::: "memory");
      __builtin_amdgcn_s_barrier();
      __builtin_amdgcn_sched_barrier(0);
    }
  }

  // ---- split-K reduce (tilebuf reused as f32 [2][64][68], 16B-aligned slots)
  __syncthreads();                        // all tile reads done before overwrite
  float* red = (float*)tilebuf;
  if (kh == 1){
    #pragma unroll
    for (int mt=0; mt<4; ++mt)
      #pragma unroll
      for (int nt=0; nt<4; ++nt){
        int off = (yr*64 + nt*16 + l15)*68 + mt*16 + lh*4;
        *(f32x4*)&red[off] = acc[mt][nt];
      }
  }
  __syncthreads();
  if (kh == 0){
    float bv[4];
    #pragma unroll
    for (int nt=0;nt<4;++nt) bv[nt] = bias[nt*16 + l15];
    const int gy = y0 + yr;
    u16* outR = out + (size_t)n*HH*WW*64 + (size_t)gy*WW*64;
    #pragma unroll
    for (int mt=0; mt<4; ++mt){
      #pragma unroll
      for (int nt=0; nt<4; ++nt){
        int off = (yr*64 + nt*16 + l15)*68 + mt*16 + lh*4;
        f32x4 p = *(const f32x4*)&red[off];
        #pragma unroll
        for (int r=0; r<4; ++r){
          int x = x0 + mt*16 + lh*4 + r;
          float v = acc[mt][nt][r] + p[r] + bv[nt];
          if (TANH) v = ftanh(v);
          outR[(size_t)x*64 + nt*16 + l15] = f2bf(v);
        }
      }
    }
  }
}

// Correlation via banded MFMA GEMM. Per block (b, y, 64-x tile):
//   G[x, j] = sum_c L[x,c] * R[j,c],  j window = [x0-128, x0+64)  (192 cols)
//   corr[d, x] = G[x, x-d] for d in [0,128)
// LDS: Lt 64x128B + Rt 192x128B (32 KB, swizzled), then reused as
// band[128][65] f32 (33 KB) for the diagonal->row transpose before store.
__global__ __launch_bounds__(256) void corr_kernel(const u16* __restrict__ phiL,
    const u16* __restrict__ phiR, const u16* __restrict__ zpad, float* __restrict__ out){
  __shared__ __align__(16) char lds[33280];
  u16* Lt = (u16*)lds;             // 8192 B
  u16* Rt = (u16*)(lds + 8192);    // 24576 B
  float* band = (float*)lds;       // 128*65 f32 = 33280 B
  const int tid = threadIdx.x;
  const int x0 = blockIdx.x*64;
  const int y  = blockIdx.y;
  const int b  = blockIdx.z;
  const u16* Lrow = phiL + ((size_t)(b*HH + y)*WW)*64;
  const u16* Rrow = phiR + ((size_t)(b*HH + y)*WW)*64;

  // stage Lt: 512 chunks, q = x*8 + j, pre-swizzled source (rule 21)
  #pragma unroll
  for (int c0=0; c0<2; ++c0){
    int q = c0*256 + tid;
    int x = q>>3, j = q&7;
    const u16* g = Lrow + (((size_t)(x0 + x))<<6) + ((j ^ (x&7))<<3);
    gload_lds16(g, &Lt[(q & ~63)*8]);
  }
  // stage Rt: 1536 chunks, col jr <-> gx = x0-128+jr
  #pragma unroll
  for (int c0=0; c0<6; ++c0){
    int q = c0*256 + tid;
    int jr = q>>3, j = q&7;
    int gx = x0 - 128 + jr;
    const u16* g = (gx >= 0) ? (Rrow + (((size_t)gx)<<6) + ((j ^ (jr&7))<<3))
                             : (zpad + (j<<3));
    gload_lds16(g, &Rt[(q & ~63)*8]);
  }
  __syncthreads();

  const int lane = tid & 63;
  const int wv   = tid >> 6;        // wave owns G cols [wv*48, wv*48+48)
  const int l15  = lane & 15;
  const int lh   = lane >> 4;
  const int xorS = (l15&7)<<4;

  f32x4 acc[4][3];
  #pragma unroll
  for (int mt=0;mt<4;++mt)
    #pragma unroll
    for (int nt=0;nt<3;++nt) acc[mt][nt] = (f32x4){0.f,0.f,0.f,0.f};

  const char* tbL = (const char*)Lt;
  const char* tbR = (const char*)Rt;
  #pragma unroll
  for (int kh=0; kh<2; ++kh){
    const int kbyte = kh*64 + lh*16;
    short8 a[4], bb[3];
    #pragma unroll
    for (int mt=0; mt<4; ++mt)
      a[mt] = *(const short8*)(tbL + (mt*16 + l15)*128 + (kbyte ^ xorS));
    #pragma unroll
    for (int nt=0; nt<3; ++nt)
      bb[nt] = *(const short8*)(tbR + (wv*48 + nt*16 + l15)*128 + (kbyte ^ xorS));
    #pragma unroll
    for (int mt=0; mt<4; ++mt)
      #pragma unroll
      for (int nt=0; nt<3; ++nt)
        acc[mt][nt] = __builtin_amdgcn_mfma_f32_16x16x32_bf16(a[mt], bb[nt], acc[mt][nt], 0,0,0);
  }
  __syncthreads();   // everyone done reading Lt/Rt

  // scatter diagonal band: x = D-row, jr = D-col, d = x - jr + 128
  #pragma unroll
  for (int mt=0; mt<4; ++mt){
    #pragma unroll
    for (int nt=0; nt<3; ++nt){
      int jr = wv*48 + nt*16 + l15;
      #pragma unroll
      for (int r=0; r<4; ++r){
        int x = mt*16 + lh*4 + r;
        int d = x - jr + 128;
        if ((unsigned)d < 128u) band[d*65 + x] = acc[mt][nt][r];
      }
    }
  }
  __syncthreads();

  // write out: 2048 float4 chunks (128 d-rows x 16), 256B contiguous per d-row
  float* ob = out + ((size_t)(b*128)*HH + (size_t)y)*WW + x0;
  #pragma unroll
  for (int it=0; it<8; ++it){
    int c = it*256 + tid;
    int d = c>>4, xq = c&15;
    const float* bp = &band[d*65 + xq*4];
    float4 v = make_float4(bp[0], bp[1], bp[2], bp[3]);
    *(float4*)&ob[(size_t)d*HH*WW + xq*4] = v;
  }
}

extern "C" void kernel_launch(void* const* d_in, const int* in_sizes, int n_in,
                              void* d_out, int out_size, void* d_ws, size_t ws_size,
                              hipStream_t stream){
  const float* l  = (const float*)d_in[0];
  const float* r  = (const float*)d_in[1];
  const float* W0 = (const float*)d_in[2];
  const float* b0 = (const float*)d_in[3];
  const float* W1 = (const float*)d_in[4];
  const float* b1 = (const float*)d_in[5];
  const float* W2 = (const float*)d_in[6];
  const float* b2 = (const float*)d_in[7];
  const float* W3 = (const float*)d_in[8];
  const float* b3 = (const float*)d_in[9];
  float* out = (float*)d_out;

  const size_t SIDE = (size_t)2*HH*WW*64;            // elements per side (NHWC bf16)
  u16* wf   = (u16*)d_ws;                            // 110592 u16
  u16* zpad = (u16*)((char*)d_ws + (1u<<20));        // 256 B zeros
  u16* BL   = (u16*)((char*)d_ws + (2u<<20));
  u16* BR   = BL + SIDE;
  u16* A    = (u16*)d_out;                           // ping scratch inside d_out

  hipMemsetAsync(zpad, 0, 256, stream);
  prep_weights<<<dim3(432), dim3(256), 0, stream>>>(W1, W2, W3, wf);

  for (int s = 0; s < 2; ++s){
    const float* img = s ? r : l;
    u16* B = s ? BR : BL;
    conv0_kernel<<<dim3(WW/256, HH, 2), dim3(256), 0, stream>>>(img, W0, b0, A);
    conv64_kernel<true ><<<dim3(WW/64, HH/2, 2), dim3(256), 0, stream>>>(A, wf + 0*36864, b1, zpad, B);
    conv64_kernel<true ><<<dim3(WW/64, HH/2, 2), dim3(256), 0, stream>>>(B, wf + 1*36864, b2, zpad, A);
    conv64_kernel<false><<<dim3(WW/64, HH/2, 2), dim3(256), 0, stream>>>(A, wf + 2*36864, b3, zpad, B);
  }

  corr_kernel<<<dim3(WW/64, HH, 2), dim3(256), 0, stream>>>(BL, BR, zpad, out);
}

// Round 14
// 1043.983 us; speedup vs baseline: 1.1399x; 1.1399x over previous
//
#include <hip/hip_runtime.h>

#define HH 384
#define WW 1280

typedef unsigned short u16;
typedef unsigned int u32;
typedef __attribute__((ext_vector_type(8))) short short8;
typedef __attribute__((ext_vector_type(8))) unsigned short u16x8;
typedef __attribute__((ext_vector_type(4))) float f32x4;

__device__ __forceinline__ float bf2f(u16 u){ union{u32 i;float f;}v; v.i=((u32)u)<<16; return v.f; }
__device__ __forceinline__ u16 f2bf(float f){ union{float f;u32 i;}v; v.f=f; u32 r=v.i+0x7fffu+((v.i>>16)&1u); return (u16)(r>>16); }
__device__ __forceinline__ float ftanh(float x){
  float e = __expf(2.0f*x);
  return 1.0f - 2.0f/(e+1.0f);
}
__device__ __forceinline__ void gload_lds16(const void* g, void* l){
  __builtin_amdgcn_global_load_lds((const __attribute__((address_space(1))) void*)g,
                                   (__attribute__((address_space(3))) void*)l, 16, 0, 0);
}

// Repack W1..W3 (OIHW f32) -> wf[layer][tap][oc][ic'] bf16, with the LDS read
// swizzle (byte ^= (oc&7)<<4) pre-inverted so linear global_load_lds staging
// lands the swizzled image: ic' = ic ^ ((oc&7)<<3).
__global__ __launch_bounds__(256) void prep_weights(const float* __restrict__ W1,
    const float* __restrict__ W2, const float* __restrict__ W3, u16* __restrict__ wf){
  int idx = blockIdx.x*256 + threadIdx.x;          // 3*9*64*64 = 110592
  if (idx >= 110592) return;
  int m    = idx & 63;
  int oc   = (idx>>6) & 63;
  int tap  = (idx>>12) % 9;
  int layer= idx / 36864;
  int ic   = m ^ ((oc&7)<<3);
  const float* Ws = layer==0 ? W1 : (layer==1 ? W2 : W3);
  wf[idx] = f2bf(Ws[(oc*64+ic)*9 + tap]);
}

// Layer 0: 3ch f32 NCHW -> 64ch bf16 NHWC, tanh. One pixel x 64 oc per thread.
__global__ __launch_bounds__(256) void conv0_kernel(const float* __restrict__ img,
    const float* __restrict__ W0, const float* __restrict__ b0, u16* __restrict__ out){
  int x = blockIdx.x*256 + threadIdx.x;
  int y = blockIdx.y;
  int n = blockIdx.z;
  const float* in = img + (size_t)n*3*HH*WW;
  float acc[64];
  #pragma unroll
  for (int o=0;o<64;++o) acc[o] = b0[o];
  #pragma unroll
  for (int ic=0; ic<3; ++ic)
  #pragma unroll
  for (int dy=0; dy<3; ++dy){
    int gy = y + dy - 1;
    #pragma unroll
    for (int dx=0; dx<3; ++dx){
      int gx = x + dx - 1;
      float v = 0.f;
      if (gy>=0 && gy<HH && (unsigned)gx < (unsigned)WW)
        v = in[((size_t)ic*HH + gy)*WW + gx];
      #pragma unroll
      for (int o=0;o<64;++o)
        acc[o] = fmaf(v, W0[(o*3+ic)*9 + dy*3 + dx], acc[o]);
    }
  }
  u16* op = out + ((size_t)((n*HH + y)*WW) + x)*64;
  #pragma unroll
  for (int cc=0; cc<8; ++cc){
    u16x8 v;
    #pragma unroll
    for (int k=0;k<8;++k) v[k] = f2bf(ftanh(acc[cc*8+k]));
    *(u16x8*)(op + cc*8) = v;
  }
}

// Layers 1-3: 64->64 conv as 9 shifted MFMA GEMMs. NHWC bf16 in/out.
// Block: 256 px (64x * 4y) x 64 oc; wave w owns y-row y0+w, M=64 N=64 (4x4 frags).
// 1-D grid with XCD-bijective swizzle: co-locates y-adjacent tiles on one XCD
// so shared halo rows hit L2. Input LDS [6 rows][66 cols][64 ic] swizzled,
// staged linearly from pre-swizzled src. Weight LDS wbuf[3], staged 2 taps
// ahead, counted-vmcnt raw barriers (no vmcnt(0) drain in the tap loop).
template<bool TANH>
__global__ __launch_bounds__(256) void conv64_kernel(const u16* __restrict__ in,
    const u16* __restrict__ wfL, const float* __restrict__ bias,
    const u16* __restrict__ zpad, u16* __restrict__ out){
  __shared__ __align__(16) u16 tile[6*66*64];      // 50688 B
  __shared__ __align__(16) u16 wbuf[3][4096];      // 3 x 8192 B
  const int tid = threadIdx.x;
  int id = blockIdx.x;
  id = (id & 7)*480 + (id >> 3);     // bijective: 3840 = 8*480
  const int x0 = (id % 20)*64;
  const int y0 = ((id / 20) % 96)*4;
  const int n  = id / 1920;
  const u16* inN = in + (size_t)n*HH*WW*64;

  // stage input tile: 3168 16B-chunks, chunk q = (row*66+col)*8 + j
  for (int q0 = 0; q0 < 3168; q0 += 256){
    int q = q0 + tid;
    if (q < 3168){
      int row = q / 528;
      int rem = q - row*528;
      int col = rem >> 3;
      int j   = rem & 7;
      int gy = y0 - 1 + row;
      int gx = x0 - 1 + col;
      const u16* g;
      if ((unsigned)gy < (unsigned)HH && (unsigned)gx < (unsigned)WW)
        g = inN + (((size_t)(gy*WW + gx))<<6) + ((j ^ (col&7))<<3);
      else
        g = zpad + (j<<3);
      gload_lds16(g, &tile[(size_t)(q & ~63)*8]);
    }
  }
  // stage weights taps 0,1 -> wbuf[0], wbuf[1]
  #pragma unroll
  for (int t=0; t<2; ++t)
    #pragma unroll
    for (int c=0; c<2; ++c){
      int q = c*256 + tid;
      gload_lds16(wfL + (size_t)t*4096 + (size_t)q*8, &wbuf[t][(q & ~63)*8]);
    }
  // drain tile + tap0 (leave tap1's 2 chunks in flight), then barrier
  asm volatile("s_waitcnt vmcnt(2)" ::: "memory");
  __builtin_amdgcn_s_barrier();
  __builtin_amdgcn_sched_barrier(0);

  const int lane = tid & 63;
  const int wv = tid >> 6;
  const int l15 = lane & 15;
  const int lh  = lane >> 4;

  f32x4 acc[4][4];
  #pragma unroll
  for (int mt=0;mt<4;++mt)
    #pragma unroll
    for (int nt=0;nt<4;++nt) acc[mt][nt] = (f32x4){0.f,0.f,0.f,0.f};

  #pragma unroll
  for (int tap = 0; tap < 9; ++tap){
    const int dy = tap/3, dx = tap%3;
    if (tap <= 6){               // prefetch tap+2 weights (2-deep pipeline)
      const u16* wsrc = wfL + (size_t)(tap+2)*4096;
      u16* wdst = wbuf[(tap+2)%3];
      #pragma unroll
      for (int c=0;c<2;++c){
        int q = c*256 + tid;
        gload_lds16(wsrc + (size_t)q*8, &wdst[(q & ~63)*8]);
      }
    }
    const char* wb = (const char*)wbuf[tap%3];
    const char* tb = (const char*)tile;
    const int xorA = ((l15 + dx)&7)<<4;
    const int xorB = (l15&7)<<4;
    #pragma unroll
    for (int kh=0; kh<2; ++kh){
      const int kbyte = kh*64 + lh*16;
      short8 a[4], b[4];
      #pragma unroll
      for (int mt=0; mt<4; ++mt){
        int col = mt*16 + l15 + dx;
        a[mt] = *(const short8*)(tb + ((wv+dy)*66 + col)*128 + (kbyte ^ xorA));
      }
      #pragma unroll
      for (int nt=0; nt<4; ++nt){
        int oc = nt*16 + l15;
        b[nt] = *(const short8*)(wb + oc*128 + (kbyte ^ xorB));
      }
      #pragma unroll
      for (int mt=0; mt<4; ++mt)
        #pragma unroll
        for (int nt=0; nt<4; ++nt)
          acc[mt][nt] = __builtin_amdgcn_mfma_f32_16x16x32_bf16(a[mt], b[nt], acc[mt][nt], 0,0,0);
    }
    if (tap < 8){
      // drain tap+1's weight writes; keep tap+2's (just issued) in flight
      if (tap <= 6) asm volatile("s_waitcnt vmcnt(2)" ::: "memory");
      else          asm volatile("s_waitcnt vmcnt(0)" ::: "memory");
      __builtin_amdgcn_s_barrier();
      __builtin_amdgcn_sched_barrier(0);
    }
  }

  float bv[4];
  #pragma unroll
  for (int nt=0;nt<4;++nt) bv[nt] = bias[nt*16 + l15];
  const int gy = y0 + wv;
  u16* outR = out + (size_t)n*HH*WW*64 + (size_t)gy*WW*64;
  #pragma unroll
  for (int mt=0; mt<4; ++mt){
    #pragma unroll
    for (int r=0; r<4; ++r){
      int x = x0 + mt*16 + lh*4 + r;
      u16* op = outR + (size_t)x*64 + l15;
      #pragma unroll
      for (int nt=0; nt<4; ++nt){
        float v = acc[mt][nt][r] + bv[nt];
        if (TANH) v = ftanh(v);
        op[nt*16] = f2bf(v);
      }
    }
  }
}

// Correlation via banded MFMA GEMM, operands straight from global (no input
// LDS: neither L nor R fragments have any cross-wave or repeat reuse).
// Per block (b, y, 64-x tile):
//   G[x, j] = sum_c L[x,c] * R[j,c],  j window = [x0-128, x0+64)  (192 cols)
//   corr[d, x] = G[x, x-d] for d in [0,128)
// LDS: band[128][65] f32 only (33 KB, 4 blocks/CU). 1-D grid, XCD-bijective
// swizzle so x/y-adjacent blocks (2/3-overlapping R windows) share L2.
__global__ __launch_bounds__(256) void corr_kernel(const u16* __restrict__ phiL,
    const u16* __restrict__ phiR, float* __restrict__ out){
  __shared__ __align__(16) float band[128*65];     // 33280 B
  const int tid = threadIdx.x;
  int id = blockIdx.x;
  id = (id & 7)*1920 + (id >> 3);    // bijective: 15360 = 8*1920
  const int x0 = (id % 20)*64;
  const int y  = (id / 20) % 384;
  const int b  = id / 7680;
  const u16* Lrow = phiL + ((size_t)(b*HH + y)*WW)*64;
  const u16* Rrow = phiR + ((size_t)(b*HH + y)*WW)*64;

  const int lane = tid & 63;
  const int wv   = tid >> 6;        // wave owns G cols [wv*48, wv*48+48)
  const int l15  = lane & 15;
  const int lh   = lane >> 4;

  f32x4 acc[4][3];
  #pragma unroll
  for (int mt=0;mt<4;++mt)
    #pragma unroll
    for (int nt=0;nt<3;++nt) acc[mt][nt] = (f32x4){0.f,0.f,0.f,0.f};

  #pragma unroll
  for (int kh=0; kh<2; ++kh){
    const int koff = kh*32 + lh*8;  // u16 units within a pixel's 64 channels
    short8 a[4], bb[3];
    #pragma unroll
    for (int mt=0; mt<4; ++mt)
      a[mt] = *(const short8*)(Lrow + (size_t)(x0 + mt*16 + l15)*64 + koff);
    #pragma unroll
    for (int nt=0; nt<3; ++nt){
      int gx = x0 - 128 + wv*48 + nt*16 + l15;
      short8 z = (short8){0,0,0,0,0,0,0,0};
      bb[nt] = (gx >= 0) ? *(const short8*)(Rrow + (size_t)gx*64 + koff) : z;
    }
    #pragma unroll
    for (int mt=0; mt<4; ++mt)
      #pragma unroll
      for (int nt=0; nt<3; ++nt)
        acc[mt][nt] = __builtin_amdgcn_mfma_f32_16x16x32_bf16(a[mt], bb[nt], acc[mt][nt], 0,0,0);
  }

  // scatter diagonal band: x = D-row, jr = D-col, d = x - jr + 128
  #pragma unroll
  for (int mt=0; mt<4; ++mt){
    #pragma unroll
    for (int nt=0; nt<3; ++nt){
      int jr = wv*48 + nt*16 + l15;
      #pragma unroll
      for (int r=0; r<4; ++r){
        int x = mt*16 + lh*4 + r;
        int d = x - jr + 128;
        if ((unsigned)d < 128u) band[d*65 + x] = acc[mt][nt][r];
      }
    }
  }
  __syncthreads();

  // write out: 2048 float4 chunks (128 d-rows x 16), 256B contiguous per d-row
  float* ob = out + ((size_t)(b*128)*HH + (size_t)y)*WW + x0;
  #pragma unroll
  for (int it=0; it<8; ++it){
    int c = it*256 + tid;
    int d = c>>4, xq = c&15;
    const float* bp = &band[d*65 + xq*4];
    float4 v = make_float4(bp[0], bp[1], bp[2], bp[3]);
    *(float4*)&ob[(size_t)d*HH*WW + xq*4] = v;
  }
}

extern "C" void kernel_launch(void* const* d_in, const int* in_sizes, int n_in,
                              void* d_out, int out_size, void* d_ws, size_t ws_size,
                              hipStream_t stream){
  const float* l  = (const float*)d_in[0];
  const float* r  = (const float*)d_in[1];
  const float* W0 = (const float*)d_in[2];
  const float* b0 = (const float*)d_in[3];
  const float* W1 = (const float*)d_in[4];
  const float* b1 = (const float*)d_in[5];
  const float* W2 = (const float*)d_in[6];
  const float* b2 = (const float*)d_in[7];
  const float* W3 = (const float*)d_in[8];
  const float* b3 = (const float*)d_in[9];
  float* out = (float*)d_out;

  const size_t SIDE = (size_t)2*HH*WW*64;            // elements per side (NHWC bf16)
  u16* wf   = (u16*)d_ws;                            // 110592 u16
  u16* zpad = (u16*)((char*)d_ws + (1u<<20));        // 256 B zeros
  u16* BL   = (u16*)((char*)d_ws + (2u<<20));
  u16* BR   = BL + SIDE;
  u16* A    = (u16*)d_out;                           // ping scratch inside d_out

  hipMemsetAsync(zpad, 0, 256, stream);
  prep_weights<<<dim3(432), dim3(256), 0, stream>>>(W1, W2, W3, wf);

  for (int s = 0; s < 2; ++s){
    const float* img = s ? r : l;
    u16* B = s ? BR : BL;
    conv0_kernel<<<dim3(WW/256, HH, 2), dim3(256), 0, stream>>>(img, W0, b0, A);
    conv64_kernel<true ><<<dim3(3840), dim3(256), 0, stream>>>(A, wf + 0*36864, b1, zpad, B);
    conv64_kernel<true ><<<dim3(3840), dim3(256), 0, stream>>>(B, wf + 1*36864, b2, zpad, A);
    conv64_kernel<false><<<dim3(3840), dim3(256), 0, stream>>>(A, wf + 2*36864, b3, zpad, B);
  }

  corr_kernel<<<dim3(15360), dim3(256), 0, stream>>>(BL, BR, out);
}